// Round 8
// baseline (672.835 us; speedup 1.0000x reference)
//
#include <hip/hip_runtime.h>
#include <hip/hip_bf16.h>

#define S3 32768          // 32^3
#define PADD 34
#define PADS (34*34*34)   // 39304
#define CC 219
#define CF 64
#define CPAD 224          // padded channel count for conv inputs
#define CIN_UP 411
#define CUPAD 416         // padded channel count for upsample input
#define ALPHA 0.1f
#define EPS_IN 1e-5f

typedef __attribute__((ext_vector_type(8))) short short8;   // 8 bf16 (4 VGPRs)
typedef __attribute__((ext_vector_type(4))) float floatx4;  // 4 fp32 acc

__device__ __forceinline__ float lrelu(float v){ return v >= 0.f ? v : ALPHA * v; }
__device__ __forceinline__ unsigned short f2bf(float f){
    unsigned int u = __builtin_bit_cast(unsigned int, f);
    u = (u + 0x7FFFu + ((u >> 16) & 1u)) >> 16;   // RNE
    return (unsigned short)u;
}
// barrier that only drains LDS ops: global-load prefetch stays in flight (AITER pattern)
#define LGKM_BARRIER() __asm__ __volatile__("s_waitcnt lgkmcnt(0)\ns_barrier" ::: "memory")

// ---------------- zero-pad src to [64][34][34][34] fp32 (for corr) ----------------
__global__ __launch_bounds__(256) void pad_kernel(const float* __restrict__ src,
                                                  float* __restrict__ dst){
    int idx = blockIdx.x * 256 + threadIdx.x;
    if (idx >= CF * PADS) return;
    int c = idx / PADS, r = idx % PADS;
    int z = r / (PADD*PADD); int r2 = r % (PADD*PADD);
    int y = r2 / PADD, x = r2 % PADD;
    float v = 0.f;
    if (z >= 1 && z <= 32 && y >= 1 && y <= 32 && x >= 1 && x <= 32)
        v = src[((c*32 + (z-1))*32 + (y-1))*32 + (x-1)];
    dst[idx] = v;
}

// ---------------- correlation volume -> Xp channels [192..219) bf16 ----------------
// 512 blocks x 256 thr = 2048 waves; 64 spatial x 4 channel-groups + LDS reduction.
__global__ __launch_bounds__(256) void corr_kernel(const float* __restrict__ tgt,
                                                   const float* __restrict__ srcp,
                                                   unsigned short* __restrict__ Xp){
    __shared__ float red[3][64][27];   // groups 1..3 partials (20.7 KB)
    const int t = threadIdx.x;
    const int s = t & 63, g = t >> 6;
    const int p = blockIdx.x * 64 + s;   // 0..32767
    const int z = p >> 10, y = (p >> 5) & 31, x = p & 31;
    float acc[27];
    #pragma unroll
    for (int k = 0; k < 27; k++) acc[k] = 0.f;
    const int pbase = ((z+1)*PADD + (y+1))*PADD + (x+1);
    const int c0 = g * 16;
    for (int c = c0; c < c0 + 16; c++){
        float tv = tgt[c*S3 + p];
        const float* sp = srcp + c*PADS + pbase;
        #pragma unroll
        for (int dz = 0; dz < 3; dz++)
            #pragma unroll
            for (int dy = 0; dy < 3; dy++)
                #pragma unroll
                for (int dx = 0; dx < 3; dx++){
                    int k = (dz*3 + dy)*3 + dx;
                    acc[k] += tv * sp[(dz-1)*(PADD*PADD) + (dy-1)*PADD + (dx-1)];
                }
    }
    if (g > 0){
        #pragma unroll
        for (int k = 0; k < 27; k++) red[g-1][s][k] = acc[k];
    }
    __syncthreads();
    if (g == 0){
        #pragma unroll
        for (int k = 0; k < 27; k++)
            acc[k] += red[0][s][k] + red[1][s][k] + red[2][s][k];
        unsigned short cv[27];
        #pragma unroll
        for (int k = 0; k < 27; k++) cv[k] = f2bf(acc[k] * (1.f/64.f));
        size_t bi = ((size_t)(z+1)*1156 + (y+1)*34 + (x+1))*CPAD + 192;
        uint4 o0, o1, o2;
        o0.x = cv[0]  | ((unsigned)cv[1]<<16);  o0.y = cv[2]  | ((unsigned)cv[3]<<16);
        o0.z = cv[4]  | ((unsigned)cv[5]<<16);  o0.w = cv[6]  | ((unsigned)cv[7]<<16);
        o1.x = cv[8]  | ((unsigned)cv[9]<<16);  o1.y = cv[10] | ((unsigned)cv[11]<<16);
        o1.z = cv[12] | ((unsigned)cv[13]<<16); o1.w = cv[14] | ((unsigned)cv[15]<<16);
        o2.x = cv[16] | ((unsigned)cv[17]<<16); o2.y = cv[18] | ((unsigned)cv[19]<<16);
        o2.z = cv[20] | ((unsigned)cv[21]<<16); o2.w = cv[22] | ((unsigned)cv[23]<<16);
        *(uint4*)&Xp[bi]      = o0;
        *(uint4*)&Xp[bi + 8]  = o1;
        *(uint4*)&Xp[bi + 16] = o2;
        *(unsigned int*)&Xp[bi + 24] = cv[24] | ((unsigned)cv[25]<<16);
        Xp[bi + 26] = cv[26];
    }
}

// ---------------- instance-norm stats: one block per channel (float4 loads) ----------------
__global__ __launch_bounds__(256) void stats_kernel(const float* __restrict__ xin,
                                                    float* __restrict__ stats, int nch){
    int c = blockIdx.x;
    const float4* p = (const float4*)(xin + (size_t)c * S3);
    float s = 0.f, s2 = 0.f;
    for (int i = threadIdx.x; i < S3/4; i += 256){
        float4 v = p[i];
        s  += v.x + v.y + v.z + v.w;
        s2 += v.x*v.x + v.y*v.y + v.z*v.z + v.w*v.w;
    }
    #pragma unroll
    for (int off = 32; off > 0; off >>= 1){
        s  += __shfl_xor(s,  off);
        s2 += __shfl_xor(s2, off);
    }
    __shared__ float ls[4], ls2[4];
    int wid = threadIdx.x >> 6;
    if ((threadIdx.x & 63) == 0){ ls[wid] = s; ls2[wid] = s2; }
    __syncthreads();
    if (threadIdx.x == 0){
        float S = 0.f, S2 = 0.f;
        #pragma unroll
        for (int w = 0; w < 4; w++){ S += ls[w]; S2 += ls2[w]; }
        float m   = S * (1.f/S3);
        float var = S2 * (1.f/S3) - m*m;
        stats[c]       = m;
        stats[nch + c] = rsqrtf(var + EPS_IN);
    }
}

// ---------------- pack fp32 [C][32^3] -> channel-last bf16 Xp[34^3][224] ----------------
// optional fused fp32 normalized output (replaces the separate norm_apply pass)
__global__ __launch_bounds__(256) void pack_kernel(const float* __restrict__ src,
        const float* __restrict__ mean, const float* __restrict__ rstd,
        unsigned short* __restrict__ Xp, float* __restrict__ fp32out,
        int Csrc, int dstbase, int donorm){
    __shared__ float sT[64*33];
    const int row = blockIdx.x;          // z*32+y
    const int chunk = blockIdx.y;
    const int t = threadIdx.x;
    {
        int c = t >> 2, xq = (t & 3) * 8;
        int csrc = chunk*64 + c;
        float4 v0 = make_float4(0.f,0.f,0.f,0.f), v1 = v0;
        float m = 0.f, r = 1.f;
        if (csrc < Csrc){
            const float4* s4 = (const float4*)&src[(size_t)csrc*S3 + row*32 + xq];
            v0 = s4[0]; v1 = s4[1];
            if (donorm){ m = mean[csrc]; r = rstd[csrc]; }
        }
        if (donorm){
            v0.x = lrelu((v0.x-m)*r); v0.y = lrelu((v0.y-m)*r);
            v0.z = lrelu((v0.z-m)*r); v0.w = lrelu((v0.w-m)*r);
            v1.x = lrelu((v1.x-m)*r); v1.y = lrelu((v1.y-m)*r);
            v1.z = lrelu((v1.z-m)*r); v1.w = lrelu((v1.w-m)*r);
        }
        if (fp32out && csrc < Csrc){
            float4* o4 = (float4*)&fp32out[(size_t)csrc*S3 + row*32 + xq];
            o4[0] = v0; o4[1] = v1;
        }
        float* sp = &sT[c*33 + xq];
        sp[0]=v0.x; sp[1]=v0.y; sp[2]=v0.z; sp[3]=v0.w;
        sp[4]=v1.x; sp[5]=v1.y; sp[6]=v1.z; sp[7]=v1.w;
    }
    __syncthreads();
    {
        int x = t >> 3, coff = (t & 7) * 8;
        int dstc = dstbase + chunk*64 + coff;
        if (dstc < CPAD){
            unsigned short u[8];
            #pragma unroll
            for (int j = 0; j < 8; j++) u[j] = f2bf(sT[(coff+j)*33 + x]);
            uint4 o;
            o.x = u[0] | ((unsigned)u[1]<<16);
            o.y = u[2] | ((unsigned)u[3]<<16);
            o.z = u[4] | ((unsigned)u[5]<<16);
            o.w = u[6] | ((unsigned)u[7]<<16);
            int z = row >> 5, y = row & 31;
            size_t pos = (size_t)(z+1)*1156 + (y+1)*34 + (x+1);
            *(uint4*)&Xp[pos*CPAD + dstc] = o;
        }
    }
}

// ---------------- pack fp32 [411][16^3] -> channel-last bf16 Cp[18^3][416] ----------------
__global__ __launch_bounds__(256) void pack16_kernel(const float* __restrict__ src,
        unsigned short* __restrict__ Cp){
    __shared__ float sT[64*17];
    const int row = blockIdx.x;   // z'*16+y'
    const int chunk = blockIdx.y; // 0..6
    const int t = threadIdx.x;
    {
        int c = t >> 2, xq = (t & 3) * 4;
        int csrc = chunk*64 + c;
        float4 v = make_float4(0.f,0.f,0.f,0.f);
        if (csrc < CIN_UP)
            v = *(const float4*)&src[(size_t)csrc*4096 + row*16 + xq];
        float* sp = &sT[c*17 + xq];
        sp[0]=v.x; sp[1]=v.y; sp[2]=v.z; sp[3]=v.w;
    }
    __syncthreads();
    {
        int x = t >> 4, coff = (t & 15) * 4;
        int dstc = chunk*64 + coff;
        if (dstc < CUPAD){
            unsigned short u0 = f2bf(sT[(coff+0)*17 + x]);
            unsigned short u1 = f2bf(sT[(coff+1)*17 + x]);
            unsigned short u2 = f2bf(sT[(coff+2)*17 + x]);
            unsigned short u3 = f2bf(sT[(coff+3)*17 + x]);
            uint2 o; o.x = u0 | ((unsigned)u1<<16); o.y = u2 | ((unsigned)u3<<16);
            int z = row >> 4, y = row & 15;
            size_t pos = (size_t)(z+1)*324 + (y+1)*18 + (x+1);
            *(uint2*)&Cp[pos*CUPAD + dstc] = o;
        }
    }
}

// ---------------- pack conv weights: Wt[step=tap*7+cb][co 256][ci 32] bf16 ----------------
__global__ __launch_bounds__(256) void wpack_kernel(const float* __restrict__ w,
        unsigned short* __restrict__ Wt, int perm){
    int idx = blockIdx.x*256 + threadIdx.x;   // < 27*7*256*32
    int ciin = idx & 31;
    int co   = (idx >> 5) & 255;
    int rest = idx >> 13;        // tap*7+cb
    int cb = rest % 7, tap = rest / 7;
    int ci = cb*32 + ciin;
    float v = 0.f;
    if (co < CC && ci < CC){
        int ciref = ci;
        if (perm) ciref = ci < 128 ? ci : (ci < 192 ? ci + 27 : ci - 64);
        v = w[((size_t)co*CC + ciref)*27 + tap];
    }
    Wt[idx] = f2bf(v);
}

// ---------------- pack out-conv weights: Wt2[tap][cb][co 16][ci 32] bf16 ----------------
__global__ __launch_bounds__(256) void wpack_out_kernel(const float* __restrict__ w,
        unsigned short* __restrict__ Wt2){
    int idx = blockIdx.x*256 + threadIdx.x;   // < 27*7*16*32 = 96768
    if (idx >= 27*7*16*32) return;
    int ciin = idx & 31;
    int co   = (idx >> 5) & 15;
    int rest = idx >> 9;        // tap*7+cb
    int cb = rest % 7, tap = rest / 7;
    int ci = cb*32 + ciin;
    float v = 0.f;
    if (co < 3 && ci < CC)
        v = w[((size_t)co*CC + ci)*27 + tap];
    Wt2[idx] = f2bf(v);
}

// ---------------- pack upsample weights: Wu[parity 8][tap 8][co 64][ci 416] bf16 ----------------
__global__ __launch_bounds__(256) void wupack_kernel(const float* __restrict__ w,
        unsigned short* __restrict__ Wu){
    int idx = blockIdx.x*256 + threadIdx.x;  // < 8*8*64*416
    int ci = idx % CUPAD;
    int rest = idx / CUPAD;
    int co = rest & 63;
    int pj = rest >> 6;
    int j = pj & 7, p = pj >> 3;
    float v = 0.f;
    if (ci < CIN_UP){
        int oz = p>>2, oy = (p>>1)&1, ox = p&1;
        int jz = j>>2, jy = (j>>1)&1, jx = j&1;
        int wz = 3 - oz - 2*jz, wy = 3 - oy - 2*jy, wx = 3 - ox - 2*jx;
        v = w[(((size_t)ci*64 + co)*64) + wz*16 + wy*4 + wx];
    }
    Wu[idx] = f2bf(v);
}

// ---------------- upsample via MFMA: per-parity GEMM M=64, N=16^3, K=8*416 ----------------
// cross-barrier staging prefetch + LGKM barriers (v8, proven).
__global__ __launch_bounds__(256,2) void ups_mfma_kernel(const unsigned short* __restrict__ Cp,
        const unsigned short* __restrict__ Wu, float* __restrict__ U){
    __shared__ unsigned short sA[64*40];
    __shared__ unsigned short sB[64*40];
    const int nt = blockIdx.x;          // 512 = parity(8) x z'(16) x ygrp(4)
    const int p  = nt >> 6;
    const int zp = (nt >> 2) & 15;
    const int y0 = (nt & 3) * 4;
    const int oz = p>>2, oy = (p>>1)&1, ox = p&1;
    const int t = threadIdx.x, w = t>>6, l = t&63;
    const int mw = (w&1)*32, nw = (w>>1)*32;
    const int lm = l&15, lq = l>>4;
    const int sn = t>>2, spart = (t&3)*8;
    const int sr = sn>>4, sx = sn&15;
    floatx4 acc[2][2];
    #pragma unroll
    for (int i=0;i<2;i++)
        #pragma unroll
        for (int j=0;j<2;j++) acc[i][j] = (floatx4){0.f,0.f,0.f,0.f};

    for (int j = 0; j < 8; ++j){
        int sz = oz + (j>>2), sy = oy + ((j>>1)&1), sxx = ox + (j&1);
        size_t pbase = ((size_t)(zp+sz)*324 + (y0+sr+sy)*18 + (sx+sxx)) * CUPAD;
        size_t abase = ((size_t)(p*8 + j)*64 + sn)*CUPAD;
        uint4 av = *(const uint4*)&Wu[abase + spart];
        uint4 bv = *(const uint4*)&Cp[pbase + spart];
        for (int cb = 0; cb < 13; ++cb){
            LGKM_BARRIER();   // prior iter's ds_reads done (ds ops only; vmcnt in flight)
            *(uint4*)&sA[sn*40 + spart] = av;
            *(uint4*)&sB[sn*40 + spart] = bv;
            if (cb < 12){
                av = *(const uint4*)&Wu[abase + (cb+1)*32 + spart];
                bv = *(const uint4*)&Cp[pbase + (cb+1)*32 + spart];
            }
            LGKM_BARRIER();   // ds_writes visible; prefetch loads continue under MFMA
            short8 af[2], bfv[2];
            #pragma unroll
            for (int i=0;i<2;i++){
                af[i]  = *(const short8*)&sA[(mw + i*16 + lm)*40 + lq*8];
                bfv[i] = *(const short8*)&sB[(nw + i*16 + lm)*40 + lq*8];
            }
            #pragma unroll
            for (int i=0;i<2;i++)
                #pragma unroll
                for (int jj=0;jj<2;jj++)
                    acc[i][jj] = __builtin_amdgcn_mfma_f32_16x16x32_bf16(af[i], bfv[jj], acc[i][jj], 0,0,0);
        }
    }
    #pragma unroll
    for (int i=0;i<2;i++){
        #pragma unroll
        for (int jj=0;jj<2;jj++){
            int n = nw + jj*16 + lm;
            int yy = y0 + (n>>4), xx = n&15;
            size_t opos = ((size_t)(2*zp+oz)<<10) + ((size_t)(2*yy+oy)<<5) + (2*xx+ox);
            #pragma unroll
            for (int r=0;r<4;r++){
                int co = mw + i*16 + lq*4 + r;
                U[(size_t)co*S3 + opos] = acc[i][jj][r];
            }
        }
    }
}

// ---------------- 3x3x3 conv via MFMA: 2-row tile, 1024 blocks, 3 waves/SIMD ----------------
// v9: occupancy via MORE BLOCKS (not bigger blocks -- v4 lesson). Tile halved to 2 y-rows:
// LDS [3z][4y][34x]x32ci stride 40 = 32,640 B -> 4 blocks/CU LDS-wise; grid (512,2)=1024
// blocks; launch_bounds(256,3) -> 170-VGPR budget (est ~145 used, pipelines keep their
// registers -- the v4 collapse needed cap<=128). Wave tile 64Mx32N: acc[4][2], 8 MFMA +
// 2 ds_read/tap. Per-CU MFMA and LDS demand unchanged; A-traffic doubles (~3.2 GB) --
// predicted new wall is L2 at ~100-105 us/dispatch. Pipelines (Aq[3] dist-3, bf[3] dist-2,
// triplet loop, setprio, LGKM barriers) carried over verbatim.
__global__ __launch_bounds__(256,3) void conv_mfma_kernel(const unsigned short* __restrict__ Xp,
        const unsigned short* __restrict__ Wt, const float* __restrict__ bg,
        float* __restrict__ Y){
    __shared__ unsigned short sB[408*40];   // 32,640 B
    const int nt = blockIdx.x;     // 0..511: z(32) x ygrp(16)
    const int mt = blockIdx.y;     // 0..1
    const int z  = nt >> 4;
    const int y0 = (nt & 15) * 2;
    const int t = threadIdx.x, w = t>>6, l = t&63;
    const int mw = (w & 1) * 64;          // 2 M-wave positions (64 ch each)
    const int nw = (w >> 1) * 32;         // 2 N-wave positions (32 cols each)
    const int lm = l & 15, lq = l >> 4;
    const unsigned short* ap = Wt + (size_t)(mt*128 + mw + lm)*32 + lq*8;

    // tap-invariant per-lane LDS read bases (bytes)
    int vB[2];
    #pragma unroll
    for (int j=0;j<2;j++){
        int n = nw + j*16 + lm;             // 0..63: row = n>>5 (2 y-rows), col = n&31
        vB[j] = ((n>>5)*34 + (n&31))*80 + lq*16;
    }
    // tap-invariant staging offsets: 408 rows x 4 quarters = 1632 uint4 (6*256 + 96)
    unsigned int goff[7]; int loff[7];
    #pragma unroll
    for (int k=0;k<7;k++){
        int idx = t + k*256;
        int p = idx >> 2, q = idx & 3;
        int zz = p / 136, rem = p % 136;
        int yy = rem / 34, x = rem - yy*34;
        goff[k] = (unsigned)((((z+zz)*1156 + (y0+yy)*34 + x)*CPAD + q*8) * 2);
        loff[k] = (p*40 + q*8) * 2;
    }
    const bool full6 = (t < 96);   // 1632 - 6*256

    floatx4 acc[4][2];
    #pragma unroll
    for (int i=0;i<4;i++)
        #pragma unroll
        for (int j=0;j<2;j++) acc[i][j] = (floatx4){0.f,0.f,0.f,0.f};

    short8 Aq[3][4];   // A parity buffers, prefetch distance 3
    short8 bf[3][2];   // B parity buffers, prefetch distance 2

    for (int cb = 0; cb < 7; ++cb){
        const unsigned short* apc = ap + (size_t)cb*8192;
        // A prologue (taps 0,1,2) issued before the barrier; LGKM never drains vmcnt.
        #pragma unroll
        for (int i=0;i<4;i++) Aq[0][i] = *(const short8*)(apc + i*512);
        #pragma unroll
        for (int i=0;i<4;i++) Aq[1][i] = *(const short8*)(apc + (size_t)57344 + i*512);
        #pragma unroll
        for (int i=0;i<4;i++) Aq[2][i] = *(const short8*)(apc + (size_t)2*57344 + i*512);

        const char* gb = (const char*)Xp + cb*64;
        LGKM_BARRIER();   // all waves finished reading previous tile (ds ops only)
        #pragma unroll
        for (int k=0;k<6;k++){
            uint4 v = *(const uint4*)(gb + goff[k]);
            *(uint4*)((char*)sB + loff[k]) = v;
        }
        if (full6){
            uint4 v = *(const uint4*)(gb + goff[6]);
            *(uint4*)((char*)sB + loff[6]) = v;
        }
        LGKM_BARRIER();   // ds_writes visible to all waves

        // B prologue: taps 0 and 1 (toff(0)=0, toff(1)=80 bytes)
        #pragma unroll
        for (int j=0;j<2;j++) bf[0][j] = *(const short8*)((const char*)sB + vB[j]);
        #pragma unroll
        for (int j=0;j<2;j++) bf[1][j] = *(const short8*)((const char*)sB + (vB[j] + 80));

        // tap body: B-prefetch(t+2) -> [prio1] MFMA(t) [prio0] -> A-prefetch(t+3).
        #define TAP_BODY(TAP, PAR) do{                                                   \
            const int tap_ = (TAP);                                                      \
            if (tap_ < 25){                                                              \
                int t2 = tap_ + 2;                                                       \
                int toff2 = ((t2/9)*136 + ((t2/3)%3)*34 + (t2%3))*80;                    \
                _Pragma("unroll")                                                        \
                for (int j=0;j<2;j++)                                                    \
                    bf[((PAR)+2)%3][j] = *(const short8*)((const char*)sB + (vB[j] + toff2));\
            }                                                                            \
            __builtin_amdgcn_s_setprio(1);                                               \
            _Pragma("unroll")                                                            \
            for (int i=0;i<4;i++)                                                        \
                _Pragma("unroll")                                                        \
                for (int j=0;j<2;j++)                                                    \
                    acc[i][j] = __builtin_amdgcn_mfma_f32_16x16x32_bf16(                 \
                        Aq[PAR][i], bf[PAR][j], acc[i][j], 0,0,0);                       \
            __builtin_amdgcn_s_setprio(0);                                               \
            if (tap_ < 24){                                                              \
                const unsigned short* pn = apc + (size_t)(tap_+3)*57344;                 \
                _Pragma("unroll")                                                        \
                for (int i=0;i<4;i++) Aq[PAR][i] = *(const short8*)(pn + i*512);         \
            }                                                                            \
        }while(0)

        #pragma unroll 1
        for (int pr = 0; pr < 9; ++pr){
            int tap = pr*3;
            TAP_BODY(tap,   0);
            TAP_BODY(tap+1, 1);
            TAP_BODY(tap+2, 2);
        }
        #undef TAP_BODY
    }
    #pragma unroll
    for (int i=0;i<4;i++){
        #pragma unroll
        for (int j=0;j<2;j++){
            const int n = nw + j*16 + lm;
            const size_t pp = ((size_t)z<<10) + ((size_t)(y0 + (n>>5))<<5) + (n&31);
            #pragma unroll
            for (int r=0;r<4;r++){
                int gm = mt*128 + mw + i*16 + lq*4 + r;
                if (gm < CC) Y[(size_t)gm*S3 + pp] = acc[i][j][r] + bg[gm];
            }
        }
    }
}

// ---------------- final 219->3 conv: persistent spatial B tile, reg-A (27 frags) ----------------
// LGKM barriers: af weight loads stay in flight across the barrier (v8, proven).
__global__ __launch_bounds__(256,2) void convout_mfma_kernel(const unsigned short* __restrict__ Xp,
        const unsigned short* __restrict__ Wt2, const float* __restrict__ bgl,
        float* __restrict__ Y){
    __shared__ unsigned short sB[612*36];   // 44,064 B: [3z][6y][34x] x 32ci (stride 36)
    const int nt = blockIdx.x;      // z(32) x ygrp(8)
    const int z  = nt >> 3;
    const int y0 = (nt & 7) * 4;
    const int t = threadIdx.x, w = t>>6, l = t&63;
    const int nw = w * 32;
    const int lm = l & 15, lq = l >> 4;
    floatx4 acc[2];
    acc[0] = (floatx4){0.f,0.f,0.f,0.f};
    acc[1] = (floatx4){0.f,0.f,0.f,0.f};

    for (int cb = 0; cb < 7; ++cb){
        LGKM_BARRIER();   // prior iter's ds_reads done (ds ops only)
        for (int idx = t; idx < 2448; idx += 256){
            int p = idx >> 2, q = idx & 3;
            int zz = p / 204, rem = p % 204;
            int yy = rem / 34, x = rem - yy*34;
            uint4 v = *(const uint4*)&Xp[((size_t)((z+zz)*1156 + (y0+yy)*34 + x))*CPAD + cb*32 + q*8];
            *(uint4*)&sB[p*36 + q*8] = v;
        }
        short8 af[27];
        {
            const unsigned short* wp = Wt2 + ((size_t)(cb*16 + lm))*32 + lq*8;
            #pragma unroll
            for (int tap = 0; tap < 27; ++tap)
                af[tap] = *(const short8*)(wp + (size_t)tap*3584);   // 7*16*32 per tap
        }
        LGKM_BARRIER();   // ds_writes visible; af loads stay in flight
        #pragma unroll
        for (int tap = 0; tap < 27; ++tap){
            const int dz = tap/9, dy = (tap/3)%3, dx = tap%3;
            #pragma unroll
            for (int j=0;j<2;j++){
                int n = nw + j*16 + lm;
                int r = n >> 5, x = n & 31;
                short8 bf = *(const short8*)&sB[(dz*204 + (r+dy)*34 + (x+dx))*36 + lq*8];
                acc[j] = __builtin_amdgcn_mfma_f32_16x16x32_bf16(af[tap], bf, acc[j], 0,0,0);
            }
        }
    }
    if (lq == 0){
        #pragma unroll
        for (int j = 0; j < 2; j++){
            int n = nw + j*16 + lm;
            size_t pp = ((size_t)z<<10) + ((size_t)(y0 + (n>>5))<<5) + (n&31);
            #pragma unroll
            for (int r = 0; r < 3; r++)
                Y[(size_t)r*S3 + pp] = acc[j][r] + bgl[r];
        }
    }
}

extern "C" void kernel_launch(void* const* d_in, const int* in_sizes, int n_in,
                              void* d_out, int out_size, void* d_ws, size_t ws_size,
                              hipStream_t stream) {
    const float* src   = (const float*)d_in[0];
    const float* tgt   = (const float*)d_in[1];
    const float* Cmat  = (const float*)d_in[2];
    const float* up_w  = (const float*)d_in[3];
    const float* c1_w  = (const float*)d_in[5];
    const float* c1_b  = (const float*)d_in[6];
    const float* c2_w  = (const float*)d_in[7];
    const float* c2_b  = (const float*)d_in[8];
    const float* out_w = (const float*)d_in[9];
    const float* out_b = (const float*)d_in[10];

    float* out = (float*)d_out;                          // Cn [219*S3] then out [3*S3]
    char* ws = (char*)d_ws;
    unsigned short* Xp = (unsigned short*)ws;            // 34^3 x 224 bf16 = 17,608,192 B
    float*  U  = (float*)(ws + 17608192);                // 64*S3 fp32 = 8,388,608 B
    unsigned short* Wt = (unsigned short*)(ws + 17608192);       // aliases U (3,096,576 B)
    unsigned short* Cp = (unsigned short*)(ws + 25996800);       // 18^3 x 416 bf16 = 4,852,224 B
    unsigned short* Wu = (unsigned short*)(ws + 25996800 + 4852224); // 3,407,872 B
    float* srcp = (float*)(ws + 25996800);               // aliases Cp/Wu (10,061,824 B)
    unsigned short* Wt2 = (unsigned short*)(ws + 25996800); // aliases srcp after corr (193,536 B)
    float* stats = (float*)(ws + 36058624);              // 2 KB

    hipMemsetAsync(Xp, 0, 17608192, stream);             // halo + pad channels
    hipMemsetAsync(Cp, 0, 4852224, stream);

    // ---- upsample (411->64, k4 s2) as 8 parity GEMMs + instance-norm + leaky ----
    pack16_kernel<<<dim3(256,7), 256, 0, stream>>>(Cmat, Cp);
    wupack_kernel<<<6656, 256, 0, stream>>>(up_w, Wu);
    ups_mfma_kernel<<<512, 256, 0, stream>>>(Cp, Wu, U);
    stats_kernel<<<64, 256, 0, stream>>>(U, stats, 64);
    pack_kernel<<<dim3(1024,1), 256, 0, stream>>>(U, stats, stats+64, Xp, nullptr, 64, 128, 1); // Cup -> ch 128..191
    // ---- concat: tgt -> ch 0..63, src -> ch 64..127 (raw) ----
    pack_kernel<<<dim3(1024,1), 256, 0, stream>>>(tgt, nullptr, nullptr, Xp, nullptr, 64, 0, 0);
    pack_kernel<<<dim3(1024,1), 256, 0, stream>>>(src, nullptr, nullptr, Xp, nullptr, 64, 64, 0);
    // ---- correlation volume -> ch 192..218 ----
    pad_kernel<<<9826, 256, 0, stream>>>(src, srcp);
    corr_kernel<<<512, 256, 0, stream>>>(tgt, srcp, Xp);
    // ---- out-conv weight pack (srcp region is free after corr) ----
    wpack_out_kernel<<<378, 256, 0, stream>>>(out_w, Wt2);
    // ---- conv1 (219->219) MFMA ----
    wpack_kernel<<<6048, 256, 0, stream>>>(c1_w, Wt, 1);
    conv_mfma_kernel<<<dim3(512,2), 256, 0, stream>>>(Xp, Wt, c1_b, out);
    stats_kernel<<<219, 256, 0, stream>>>(out, stats, 219);
    pack_kernel<<<dim3(1024,4), 256, 0, stream>>>(out, stats, stats+219, Xp, nullptr, 219, 0, 1);
    // ---- conv2 (219->219) MFMA ----
    wpack_kernel<<<6048, 256, 0, stream>>>(c2_w, Wt, 0);
    conv_mfma_kernel<<<dim3(512,2), 256, 0, stream>>>(Xp, Wt, c2_b, out);
    // ---- norm + leaky fused: bf16 packed Cn to Xp AND fp32 Cn to d_out in one pass ----
    stats_kernel<<<219, 256, 0, stream>>>(out, stats, 219);
    pack_kernel<<<dim3(1024,4), 256, 0, stream>>>(out, stats, stats+219, Xp, out, 219, 0, 1);
    // ---- final 219->3 conv via MFMA ----
    convout_mfma_kernel<<<256, 256, 0, stream>>>(Xp, Wt2, out_b, out + (size_t)CC*S3);
}

// Round 9
// 599.614 us; speedup vs baseline: 1.1221x; 1.1221x over previous
//
#include <hip/hip_runtime.h>
#include <hip/hip_bf16.h>

#define S3 32768          // 32^3
#define PADD 34
#define PADS (34*34*34)   // 39304
#define CC 219
#define CF 64
#define CPAD 224          // padded channel count for conv inputs
#define CIN_UP 411
#define CUPAD 416         // padded channel count for upsample input
#define ALPHA 0.1f
#define EPS_IN 1e-5f

typedef __attribute__((ext_vector_type(8))) short short8;   // 8 bf16 (4 VGPRs)
typedef __attribute__((ext_vector_type(4))) float floatx4;  // 4 fp32 acc

__device__ __forceinline__ float lrelu(float v){ return v >= 0.f ? v : ALPHA * v; }
__device__ __forceinline__ unsigned short f2bf(float f){
    unsigned int u = __builtin_bit_cast(unsigned int, f);
    u = (u + 0x7FFFu + ((u >> 16) & 1u)) >> 16;   // RNE
    return (unsigned short)u;
}
// barrier that only drains LDS ops: global-load prefetch stays in flight (AITER pattern)
#define LGKM_BARRIER() __asm__ __volatile__("s_waitcnt lgkmcnt(0)\ns_barrier" ::: "memory")

// ---------------- zero-pad src to [64][34][34][34] fp32 (for corr) ----------------
__global__ __launch_bounds__(256) void pad_kernel(const float* __restrict__ src,
                                                  float* __restrict__ dst){
    int idx = blockIdx.x * 256 + threadIdx.x;
    if (idx >= CF * PADS) return;
    int c = idx / PADS, r = idx % PADS;
    int z = r / (PADD*PADD); int r2 = r % (PADD*PADD);
    int y = r2 / PADD, x = r2 % PADD;
    float v = 0.f;
    if (z >= 1 && z <= 32 && y >= 1 && y <= 32 && x >= 1 && x <= 32)
        v = src[((c*32 + (z-1))*32 + (y-1))*32 + (x-1)];
    dst[idx] = v;
}

// ---------------- correlation volume -> Xp channels [192..219) bf16 ----------------
// 512 blocks x 256 thr = 2048 waves; 64 spatial x 4 channel-groups + LDS reduction.
__global__ __launch_bounds__(256) void corr_kernel(const float* __restrict__ tgt,
                                                   const float* __restrict__ srcp,
                                                   unsigned short* __restrict__ Xp){
    __shared__ float red[3][64][27];   // groups 1..3 partials (20.7 KB)
    const int t = threadIdx.x;
    const int s = t & 63, g = t >> 6;
    const int p = blockIdx.x * 64 + s;   // 0..32767
    const int z = p >> 10, y = (p >> 5) & 31, x = p & 31;
    float acc[27];
    #pragma unroll
    for (int k = 0; k < 27; k++) acc[k] = 0.f;
    const int pbase = ((z+1)*PADD + (y+1))*PADD + (x+1);
    const int c0 = g * 16;
    for (int c = c0; c < c0 + 16; c++){
        float tv = tgt[c*S3 + p];
        const float* sp = srcp + c*PADS + pbase;
        #pragma unroll
        for (int dz = 0; dz < 3; dz++)
            #pragma unroll
            for (int dy = 0; dy < 3; dy++)
                #pragma unroll
                for (int dx = 0; dx < 3; dx++){
                    int k = (dz*3 + dy)*3 + dx;
                    acc[k] += tv * sp[(dz-1)*(PADD*PADD) + (dy-1)*PADD + (dx-1)];
                }
    }
    if (g > 0){
        #pragma unroll
        for (int k = 0; k < 27; k++) red[g-1][s][k] = acc[k];
    }
    __syncthreads();
    if (g == 0){
        #pragma unroll
        for (int k = 0; k < 27; k++)
            acc[k] += red[0][s][k] + red[1][s][k] + red[2][s][k];
        unsigned short cv[27];
        #pragma unroll
        for (int k = 0; k < 27; k++) cv[k] = f2bf(acc[k] * (1.f/64.f));
        size_t bi = ((size_t)(z+1)*1156 + (y+1)*34 + (x+1))*CPAD + 192;
        uint4 o0, o1, o2;
        o0.x = cv[0]  | ((unsigned)cv[1]<<16);  o0.y = cv[2]  | ((unsigned)cv[3]<<16);
        o0.z = cv[4]  | ((unsigned)cv[5]<<16);  o0.w = cv[6]  | ((unsigned)cv[7]<<16);
        o1.x = cv[8]  | ((unsigned)cv[9]<<16);  o1.y = cv[10] | ((unsigned)cv[11]<<16);
        o1.z = cv[12] | ((unsigned)cv[13]<<16); o1.w = cv[14] | ((unsigned)cv[15]<<16);
        o2.x = cv[16] | ((unsigned)cv[17]<<16); o2.y = cv[18] | ((unsigned)cv[19]<<16);
        o2.z = cv[20] | ((unsigned)cv[21]<<16); o2.w = cv[22] | ((unsigned)cv[23]<<16);
        *(uint4*)&Xp[bi]      = o0;
        *(uint4*)&Xp[bi + 8]  = o1;
        *(uint4*)&Xp[bi + 16] = o2;
        *(unsigned int*)&Xp[bi + 24] = cv[24] | ((unsigned)cv[25]<<16);
        Xp[bi + 26] = cv[26];
    }
}

// ---------------- instance-norm stats: one block per channel (float4 loads) ----------------
__global__ __launch_bounds__(256) void stats_kernel(const float* __restrict__ xin,
                                                    float* __restrict__ stats, int nch){
    int c = blockIdx.x;
    const float4* p = (const float4*)(xin + (size_t)c * S3);
    float s = 0.f, s2 = 0.f;
    for (int i = threadIdx.x; i < S3/4; i += 256){
        float4 v = p[i];
        s  += v.x + v.y + v.z + v.w;
        s2 += v.x*v.x + v.y*v.y + v.z*v.z + v.w*v.w;
    }
    #pragma unroll
    for (int off = 32; off > 0; off >>= 1){
        s  += __shfl_xor(s,  off);
        s2 += __shfl_xor(s2, off);
    }
    __shared__ float ls[4], ls2[4];
    int wid = threadIdx.x >> 6;
    if ((threadIdx.x & 63) == 0){ ls[wid] = s; ls2[wid] = s2; }
    __syncthreads();
    if (threadIdx.x == 0){
        float S = 0.f, S2 = 0.f;
        #pragma unroll
        for (int w = 0; w < 4; w++){ S += ls[w]; S2 += ls2[w]; }
        float m   = S * (1.f/S3);
        float var = S2 * (1.f/S3) - m*m;
        stats[c]       = m;
        stats[nch + c] = rsqrtf(var + EPS_IN);
    }
}

// ---------------- pack fp32 [C][32^3] -> channel-last bf16 Xp[34^3][224] ----------------
// optional fused fp32 normalized output (replaces the separate norm_apply pass)
__global__ __launch_bounds__(256) void pack_kernel(const float* __restrict__ src,
        const float* __restrict__ mean, const float* __restrict__ rstd,
        unsigned short* __restrict__ Xp, float* __restrict__ fp32out,
        int Csrc, int dstbase, int donorm){
    __shared__ float sT[64*33];
    const int row = blockIdx.x;          // z*32+y
    const int chunk = blockIdx.y;
    const int t = threadIdx.x;
    {
        int c = t >> 2, xq = (t & 3) * 8;
        int csrc = chunk*64 + c;
        float4 v0 = make_float4(0.f,0.f,0.f,0.f), v1 = v0;
        float m = 0.f, r = 1.f;
        if (csrc < Csrc){
            const float4* s4 = (const float4*)&src[(size_t)csrc*S3 + row*32 + xq];
            v0 = s4[0]; v1 = s4[1];
            if (donorm){ m = mean[csrc]; r = rstd[csrc]; }
        }
        if (donorm){
            v0.x = lrelu((v0.x-m)*r); v0.y = lrelu((v0.y-m)*r);
            v0.z = lrelu((v0.z-m)*r); v0.w = lrelu((v0.w-m)*r);
            v1.x = lrelu((v1.x-m)*r); v1.y = lrelu((v1.y-m)*r);
            v1.z = lrelu((v1.z-m)*r); v1.w = lrelu((v1.w-m)*r);
        }
        if (fp32out && csrc < Csrc){
            float4* o4 = (float4*)&fp32out[(size_t)csrc*S3 + row*32 + xq];
            o4[0] = v0; o4[1] = v1;
        }
        float* sp = &sT[c*33 + xq];
        sp[0]=v0.x; sp[1]=v0.y; sp[2]=v0.z; sp[3]=v0.w;
        sp[4]=v1.x; sp[5]=v1.y; sp[6]=v1.z; sp[7]=v1.w;
    }
    __syncthreads();
    {
        int x = t >> 3, coff = (t & 7) * 8;
        int dstc = dstbase + chunk*64 + coff;
        if (dstc < CPAD){
            unsigned short u[8];
            #pragma unroll
            for (int j = 0; j < 8; j++) u[j] = f2bf(sT[(coff+j)*33 + x]);
            uint4 o;
            o.x = u[0] | ((unsigned)u[1]<<16);
            o.y = u[2] | ((unsigned)u[3]<<16);
            o.z = u[4] | ((unsigned)u[5]<<16);
            o.w = u[6] | ((unsigned)u[7]<<16);
            int z = row >> 5, y = row & 31;
            size_t pos = (size_t)(z+1)*1156 + (y+1)*34 + (x+1);
            *(uint4*)&Xp[pos*CPAD + dstc] = o;
        }
    }
}

// ---------------- pack fp32 [411][16^3] -> channel-last bf16 Cp[18^3][416] ----------------
__global__ __launch_bounds__(256) void pack16_kernel(const float* __restrict__ src,
        unsigned short* __restrict__ Cp){
    __shared__ float sT[64*17];
    const int row = blockIdx.x;   // z'*16+y'
    const int chunk = blockIdx.y; // 0..6
    const int t = threadIdx.x;
    {
        int c = t >> 2, xq = (t & 3) * 4;
        int csrc = chunk*64 + c;
        float4 v = make_float4(0.f,0.f,0.f,0.f);
        if (csrc < CIN_UP)
            v = *(const float4*)&src[(size_t)csrc*4096 + row*16 + xq];
        float* sp = &sT[c*17 + xq];
        sp[0]=v.x; sp[1]=v.y; sp[2]=v.z; sp[3]=v.w;
    }
    __syncthreads();
    {
        int x = t >> 4, coff = (t & 15) * 4;
        int dstc = chunk*64 + coff;
        if (dstc < CUPAD){
            unsigned short u0 = f2bf(sT[(coff+0)*17 + x]);
            unsigned short u1 = f2bf(sT[(coff+1)*17 + x]);
            unsigned short u2 = f2bf(sT[(coff+2)*17 + x]);
            unsigned short u3 = f2bf(sT[(coff+3)*17 + x]);
            uint2 o; o.x = u0 | ((unsigned)u1<<16); o.y = u2 | ((unsigned)u3<<16);
            int z = row >> 4, y = row & 15;
            size_t pos = (size_t)(z+1)*324 + (y+1)*18 + (x+1);
            *(uint2*)&Cp[pos*CUPAD + dstc] = o;
        }
    }
}

// ---------------- pack conv weights: Wt[step=tap*7+cb][co 256][ci 32] bf16 ----------------
__global__ __launch_bounds__(256) void wpack_kernel(const float* __restrict__ w,
        unsigned short* __restrict__ Wt, int perm){
    int idx = blockIdx.x*256 + threadIdx.x;   // < 27*7*256*32
    int ciin = idx & 31;
    int co   = (idx >> 5) & 255;
    int rest = idx >> 13;        // tap*7+cb
    int cb = rest % 7, tap = rest / 7;
    int ci = cb*32 + ciin;
    float v = 0.f;
    if (co < CC && ci < CC){
        int ciref = ci;
        if (perm) ciref = ci < 128 ? ci : (ci < 192 ? ci + 27 : ci - 64);
        v = w[((size_t)co*CC + ciref)*27 + tap];
    }
    Wt[idx] = f2bf(v);
}

// ---------------- pack out-conv weights: Wt2[tap][cb][co 16][ci 32] bf16 ----------------
__global__ __launch_bounds__(256) void wpack_out_kernel(const float* __restrict__ w,
        unsigned short* __restrict__ Wt2){
    int idx = blockIdx.x*256 + threadIdx.x;   // < 27*7*16*32 = 96768
    if (idx >= 27*7*16*32) return;
    int ciin = idx & 31;
    int co   = (idx >> 5) & 15;
    int rest = idx >> 9;        // tap*7+cb
    int cb = rest % 7, tap = rest / 7;
    int ci = cb*32 + ciin;
    float v = 0.f;
    if (co < 3 && ci < CC)
        v = w[((size_t)co*CC + ci)*27 + tap];
    Wt2[idx] = f2bf(v);
}

// ---------------- pack upsample weights: Wu[parity 8][tap 8][co 64][ci 416] bf16 ----------------
__global__ __launch_bounds__(256) void wupack_kernel(const float* __restrict__ w,
        unsigned short* __restrict__ Wu){
    int idx = blockIdx.x*256 + threadIdx.x;  // < 8*8*64*416
    int ci = idx % CUPAD;
    int rest = idx / CUPAD;
    int co = rest & 63;
    int pj = rest >> 6;
    int j = pj & 7, p = pj >> 3;
    float v = 0.f;
    if (ci < CIN_UP){
        int oz = p>>2, oy = (p>>1)&1, ox = p&1;
        int jz = j>>2, jy = (j>>1)&1, jx = j&1;
        int wz = 3 - oz - 2*jz, wy = 3 - oy - 2*jy, wx = 3 - ox - 2*jx;
        v = w[(((size_t)ci*64 + co)*64) + wz*16 + wy*4 + wx];
    }
    Wu[idx] = f2bf(v);
}

// ---------------- upsample via MFMA: per-parity GEMM M=64, N=16^3, K=8*416 ----------------
// cross-barrier staging prefetch + LGKM barriers (v8, proven).
__global__ __launch_bounds__(256,2) void ups_mfma_kernel(const unsigned short* __restrict__ Cp,
        const unsigned short* __restrict__ Wu, float* __restrict__ U){
    __shared__ unsigned short sA[64*40];
    __shared__ unsigned short sB[64*40];
    const int nt = blockIdx.x;          // 512 = parity(8) x z'(16) x ygrp(4)
    const int p  = nt >> 6;
    const int zp = (nt >> 2) & 15;
    const int y0 = (nt & 3) * 4;
    const int oz = p>>2, oy = (p>>1)&1, ox = p&1;
    const int t = threadIdx.x, w = t>>6, l = t&63;
    const int mw = (w&1)*32, nw = (w>>1)*32;
    const int lm = l&15, lq = l>>4;
    const int sn = t>>2, spart = (t&3)*8;
    const int sr = sn>>4, sx = sn&15;
    floatx4 acc[2][2];
    #pragma unroll
    for (int i=0;i<2;i++)
        #pragma unroll
        for (int j=0;j<2;j++) acc[i][j] = (floatx4){0.f,0.f,0.f,0.f};

    for (int j = 0; j < 8; ++j){
        int sz = oz + (j>>2), sy = oy + ((j>>1)&1), sxx = ox + (j&1);
        size_t pbase = ((size_t)(zp+sz)*324 + (y0+sr+sy)*18 + (sx+sxx)) * CUPAD;
        size_t abase = ((size_t)(p*8 + j)*64 + sn)*CUPAD;
        uint4 av = *(const uint4*)&Wu[abase + spart];
        uint4 bv = *(const uint4*)&Cp[pbase + spart];
        for (int cb = 0; cb < 13; ++cb){
            LGKM_BARRIER();   // prior iter's ds_reads done (ds ops only; vmcnt in flight)
            *(uint4*)&sA[sn*40 + spart] = av;
            *(uint4*)&sB[sn*40 + spart] = bv;
            if (cb < 12){
                av = *(const uint4*)&Wu[abase + (cb+1)*32 + spart];
                bv = *(const uint4*)&Cp[pbase + (cb+1)*32 + spart];
            }
            LGKM_BARRIER();   // ds_writes visible; prefetch loads continue under MFMA
            short8 af[2], bfv[2];
            #pragma unroll
            for (int i=0;i<2;i++){
                af[i]  = *(const short8*)&sA[(mw + i*16 + lm)*40 + lq*8];
                bfv[i] = *(const short8*)&sB[(nw + i*16 + lm)*40 + lq*8];
            }
            #pragma unroll
            for (int i=0;i<2;i++)
                #pragma unroll
                for (int jj=0;jj<2;jj++)
                    acc[i][jj] = __builtin_amdgcn_mfma_f32_16x16x32_bf16(af[i], bfv[jj], acc[i][jj], 0,0,0);
        }
    }
    #pragma unroll
    for (int i=0;i<2;i++){
        #pragma unroll
        for (int jj=0;jj<2;jj++){
            int n = nw + jj*16 + lm;
            int yy = y0 + (n>>4), xx = n&15;
            size_t opos = ((size_t)(2*zp+oz)<<10) + ((size_t)(2*yy+oy)<<5) + (2*xx+ox);
            #pragma unroll
            for (int r=0;r<4;r++){
                int co = mw + i*16 + lq*4 + r;
                U[(size_t)co*S3 + opos] = acc[i][jj][r];
            }
        }
    }
}

// ---------------- 3x3x3 conv via MFMA: 8-wave blocks, RELAXED bounds, 4 waves/SIMD ----------------
// v10: 512-thr / 8-wave blocks with launch_bounds(512,2) -- the ONLY bound regime that has
// ever kept the prefetch pipelines in registers (v4: (512,4) cap128 -> VGPR 52 collapse;
// v9: (256,3) cap170 -> VGPR 80 collapse; v8: (256,2) relaxed -> VGPR 120 OK).
// Same 4-row LDS tile (49KB) and grid (256,2)=512 blocks: 2 blocks/CU resident (LDS 98KB,
// VGPR ~150x4waves/SIMD=600 <= 2048 pool) -> 16 waves/CU = 4 waves/SIMD, no tail.
// Wave tile 32Mx64N (4 M-waves x 2 N-waves): per-CU A-traffic/tap = 16x256B = 4KB -- SAME
// as v8 (v9's doubling avoided); B-LDS reads 8KB/tap-slot vs CU aggregate 256B/clk = fine.
// Pipelines verbatim: Aq[3][2] dist-3, bf[3][4] dist-2, triplet loop, setprio, LGKM barriers.
__global__ __launch_bounds__(512,2) void conv_mfma_kernel(const unsigned short* __restrict__ Xp,
        const unsigned short* __restrict__ Wt, const float* __restrict__ bg,
        float* __restrict__ Y){
    __shared__ unsigned short sB[612*40];   // 48,960 B
    const int nt = blockIdx.x;     // 0..255: z(32) x ygrp(8)
    const int mt = blockIdx.y;     // 0..1
    const int z  = nt >> 3;
    const int y0 = (nt & 7) * 4;
    const int t = threadIdx.x, w = t>>6, l = t&63;
    const int mw  = (w >> 1) * 32;        // 4 M-wave positions (32 ch each)
    const int nwv = (w & 1) * 64;         // 2 N-wave positions (64 cols each)
    const int lm = l & 15, lq = l >> 4;
    const unsigned short* ap = Wt + (size_t)(mt*128 + mw + lm)*32 + lq*8;

    // tap-invariant per-lane LDS read bases (bytes)
    int vB[4];
    #pragma unroll
    for (int j=0;j<4;j++){
        int n = nwv + j*16 + lm;            // 0..127: row = n>>5 (4 y-rows), col = n&31
        vB[j] = ((n>>5)*34 + (n&31))*80 + lq*16;
    }
    // tap-invariant staging offsets: 2448 uint4 over 512 threads: 4 full + 400
    unsigned int goff[5]; int loff[5];
    #pragma unroll
    for (int k=0;k<5;k++){
        int idx = t + k*512;
        int p = idx >> 2, q = idx & 3;
        int zz = p / 204, rem = p % 204;
        int yy = rem / 34, x = rem - yy*34;
        goff[k] = (unsigned)((((z+zz)*1156 + (y0+yy)*34 + x)*CPAD + q*8) * 2);
        loff[k] = (p*40 + q*8) * 2;
    }
    const bool full4 = (t < 400);   // 2448 - 4*512

    floatx4 acc[2][4];
    #pragma unroll
    for (int i=0;i<2;i++)
        #pragma unroll
        for (int j=0;j<4;j++) acc[i][j] = (floatx4){0.f,0.f,0.f,0.f};

    short8 Aq[3][2];   // A parity buffers (32M -> 2 frags), prefetch distance 3
    short8 bf[3][4];   // B parity buffers (64N -> 4 frags), prefetch distance 2

    for (int cb = 0; cb < 7; ++cb){
        const unsigned short* apc = ap + (size_t)cb*8192;
        // A prologue (taps 0,1,2) issued before the barrier; LGKM never drains vmcnt.
        #pragma unroll
        for (int i=0;i<2;i++) Aq[0][i] = *(const short8*)(apc + i*512);
        #pragma unroll
        for (int i=0;i<2;i++) Aq[1][i] = *(const short8*)(apc + (size_t)57344 + i*512);
        #pragma unroll
        for (int i=0;i<2;i++) Aq[2][i] = *(const short8*)(apc + (size_t)2*57344 + i*512);

        const char* gb = (const char*)Xp + cb*64;
        LGKM_BARRIER();   // all waves finished reading previous tile (ds ops only)
        #pragma unroll
        for (int k=0;k<4;k++){
            uint4 v = *(const uint4*)(gb + goff[k]);
            *(uint4*)((char*)sB + loff[k]) = v;
        }
        if (full4){
            uint4 v = *(const uint4*)(gb + goff[4]);
            *(uint4*)((char*)sB + loff[4]) = v;
        }
        LGKM_BARRIER();   // ds_writes visible to all waves

        // B prologue: taps 0 and 1 (toff(0)=0, toff(1)=80 bytes)
        #pragma unroll
        for (int j=0;j<4;j++) bf[0][j] = *(const short8*)((const char*)sB + vB[j]);
        #pragma unroll
        for (int j=0;j<4;j++) bf[1][j] = *(const short8*)((const char*)sB + (vB[j] + 80));

        // tap body: B-prefetch(t+2) -> [prio1] MFMA(t) [prio0] -> A-prefetch(t+3).
        #define TAP_BODY(TAP, PAR) do{                                                   \
            const int tap_ = (TAP);                                                      \
            if (tap_ < 25){                                                              \
                int t2 = tap_ + 2;                                                       \
                int toff2 = ((t2/9)*204 + ((t2/3)%3)*34 + (t2%3))*80;                    \
                _Pragma("unroll")                                                        \
                for (int j=0;j<4;j++)                                                    \
                    bf[((PAR)+2)%3][j] = *(const short8*)((const char*)sB + (vB[j] + toff2));\
            }                                                                            \
            __builtin_amdgcn_s_setprio(1);                                               \
            _Pragma("unroll")                                                            \
            for (int i=0;i<2;i++)                                                        \
                _Pragma("unroll")                                                        \
                for (int j=0;j<4;j++)                                                    \
                    acc[i][j] = __builtin_amdgcn_mfma_f32_16x16x32_bf16(                 \
                        Aq[PAR][i], bf[PAR][j], acc[i][j], 0,0,0);                       \
            __builtin_amdgcn_s_setprio(0);                                               \
            if (tap_ < 24){                                                              \
                const unsigned short* pn = apc + (size_t)(tap_+3)*57344;                 \
                _Pragma("unroll")                                                        \
                for (int i=0;i<2;i++) Aq[PAR][i] = *(const short8*)(pn + i*512);         \
            }                                                                            \
        }while(0)

        #pragma unroll 1
        for (int pr = 0; pr < 9; ++pr){
            int tap = pr*3;
            TAP_BODY(tap,   0);
            TAP_BODY(tap+1, 1);
            TAP_BODY(tap+2, 2);
        }
        #undef TAP_BODY
    }
    #pragma unroll
    for (int i=0;i<2;i++){
        #pragma unroll
        for (int j=0;j<4;j++){
            const int n = nwv + j*16 + lm;
            const size_t pp = ((size_t)z<<10) + ((size_t)(y0 + (n>>5))<<5) + (n&31);
            #pragma unroll
            for (int r=0;r<4;r++){
                int gm = mt*128 + mw + i*16 + lq*4 + r;
                if (gm < CC) Y[(size_t)gm*S3 + pp] = acc[i][j][r] + bg[gm];
            }
        }
    }
}

// ---------------- final 219->3 conv: persistent spatial B tile, reg-A (27 frags) ----------------
// LGKM barriers: af weight loads stay in flight across the barrier (v8, proven).
__global__ __launch_bounds__(256,2) void convout_mfma_kernel(const unsigned short* __restrict__ Xp,
        const unsigned short* __restrict__ Wt2, const float* __restrict__ bgl,
        float* __restrict__ Y){
    __shared__ unsigned short sB[612*36];   // 44,064 B: [3z][6y][34x] x 32ci (stride 36)
    const int nt = blockIdx.x;      // z(32) x ygrp(8)
    const int z  = nt >> 3;
    const int y0 = (nt & 7) * 4;
    const int t = threadIdx.x, w = t>>6, l = t&63;
    const int nw = w * 32;
    const int lm = l & 15, lq = l >> 4;
    floatx4 acc[2];
    acc[0] = (floatx4){0.f,0.f,0.f,0.f};
    acc[1] = (floatx4){0.f,0.f,0.f,0.f};

    for (int cb = 0; cb < 7; ++cb){
        LGKM_BARRIER();   // prior iter's ds_reads done (ds ops only)
        for (int idx = t; idx < 2448; idx += 256){
            int p = idx >> 2, q = idx & 3;
            int zz = p / 204, rem = p % 204;
            int yy = rem / 34, x = rem - yy*34;
            uint4 v = *(const uint4*)&Xp[((size_t)((z+zz)*1156 + (y0+yy)*34 + x))*CPAD + cb*32 + q*8];
            *(uint4*)&sB[p*36 + q*8] = v;
        }
        short8 af[27];
        {
            const unsigned short* wp = Wt2 + ((size_t)(cb*16 + lm))*32 + lq*8;
            #pragma unroll
            for (int tap = 0; tap < 27; ++tap)
                af[tap] = *(const short8*)(wp + (size_t)tap*3584);   // 7*16*32 per tap
        }
        LGKM_BARRIER();   // ds_writes visible; af loads stay in flight
        #pragma unroll
        for (int tap = 0; tap < 27; ++tap){
            const int dz = tap/9, dy = (tap/3)%3, dx = tap%3;
            #pragma unroll
            for (int j=0;j<2;j++){
                int n = nw + j*16 + lm;
                int r = n >> 5, x = n & 31;
                short8 bf = *(const short8*)&sB[(dz*204 + (r+dy)*34 + (x+dx))*36 + lq*8];
                acc[j] = __builtin_amdgcn_mfma_f32_16x16x32_bf16(af[tap], bf, acc[j], 0,0,0);
            }
        }
    }
    if (lq == 0){
        #pragma unroll
        for (int j = 0; j < 2; j++){
            int n = nw + j*16 + lm;
            size_t pp = ((size_t)z<<10) + ((size_t)(y0 + (n>>5))<<5) + (n&31);
            #pragma unroll
            for (int r = 0; r < 3; r++)
                Y[(size_t)r*S3 + pp] = acc[j][r] + bgl[r];
        }
    }
}

extern "C" void kernel_launch(void* const* d_in, const int* in_sizes, int n_in,
                              void* d_out, int out_size, void* d_ws, size_t ws_size,
                              hipStream_t stream) {
    const float* src   = (const float*)d_in[0];
    const float* tgt   = (const float*)d_in[1];
    const float* Cmat  = (const float*)d_in[2];
    const float* up_w  = (const float*)d_in[3];
    const float* c1_w  = (const float*)d_in[5];
    const float* c1_b  = (const float*)d_in[6];
    const float* c2_w  = (const float*)d_in[7];
    const float* c2_b  = (const float*)d_in[8];
    const float* out_w = (const float*)d_in[9];
    const float* out_b = (const float*)d_in[10];

    float* out = (float*)d_out;                          // Cn [219*S3] then out [3*S3]
    char* ws = (char*)d_ws;
    unsigned short* Xp = (unsigned short*)ws;            // 34^3 x 224 bf16 = 17,608,192 B
    float*  U  = (float*)(ws + 17608192);                // 64*S3 fp32 = 8,388,608 B
    unsigned short* Wt = (unsigned short*)(ws + 17608192);       // aliases U (3,096,576 B)
    unsigned short* Cp = (unsigned short*)(ws + 25996800);       // 18^3 x 416 bf16 = 4,852,224 B
    unsigned short* Wu = (unsigned short*)(ws + 25996800 + 4852224); // 3,407,872 B
    float* srcp = (float*)(ws + 25996800);               // aliases Cp/Wu (10,061,824 B)
    unsigned short* Wt2 = (unsigned short*)(ws + 25996800); // aliases srcp after corr (193,536 B)
    float* stats = (float*)(ws + 36058624);              // 2 KB

    hipMemsetAsync(Xp, 0, 17608192, stream);             // halo + pad channels
    hipMemsetAsync(Cp, 0, 4852224, stream);

    // ---- upsample (411->64, k4 s2) as 8 parity GEMMs + instance-norm + leaky ----
    pack16_kernel<<<dim3(256,7), 256, 0, stream>>>(Cmat, Cp);
    wupack_kernel<<<6656, 256, 0, stream>>>(up_w, Wu);
    ups_mfma_kernel<<<512, 256, 0, stream>>>(Cp, Wu, U);
    stats_kernel<<<64, 256, 0, stream>>>(U, stats, 64);
    pack_kernel<<<dim3(1024,1), 256, 0, stream>>>(U, stats, stats+64, Xp, nullptr, 64, 128, 1); // Cup -> ch 128..191
    // ---- concat: tgt -> ch 0..63, src -> ch 64..127 (raw) ----
    pack_kernel<<<dim3(1024,1), 256, 0, stream>>>(tgt, nullptr, nullptr, Xp, nullptr, 64, 0, 0);
    pack_kernel<<<dim3(1024,1), 256, 0, stream>>>(src, nullptr, nullptr, Xp, nullptr, 64, 64, 0);
    // ---- correlation volume -> ch 192..218 ----
    pad_kernel<<<9826, 256, 0, stream>>>(src, srcp);
    corr_kernel<<<512, 256, 0, stream>>>(tgt, srcp, Xp);
    // ---- out-conv weight pack (srcp region is free after corr) ----
    wpack_out_kernel<<<378, 256, 0, stream>>>(out_w, Wt2);
    // ---- conv1 (219->219) MFMA ----
    wpack_kernel<<<6048, 256, 0, stream>>>(c1_w, Wt, 1);
    conv_mfma_kernel<<<dim3(256,2), 512, 0, stream>>>(Xp, Wt, c1_b, out);
    stats_kernel<<<219, 256, 0, stream>>>(out, stats, 219);
    pack_kernel<<<dim3(1024,4), 256, 0, stream>>>(out, stats, stats+219, Xp, nullptr, 219, 0, 1);
    // ---- conv2 (219->219) MFMA ----
    wpack_kernel<<<6048, 256, 0, stream>>>(c2_w, Wt, 0);
    conv_mfma_kernel<<<dim3(256,2), 512, 0, stream>>>(Xp, Wt, c2_b, out);
    // ---- norm + leaky fused: bf16 packed Cn to Xp AND fp32 Cn to d_out in one pass ----
    stats_kernel<<<219, 256, 0, stream>>>(out, stats, 219);
    pack_kernel<<<dim3(1024,4), 256, 0, stream>>>(out, stats, stats+219, Xp, out, 219, 0, 1);
    // ---- final 219->3 conv via MFMA ----
    convout_mfma_kernel<<<256, 256, 0, stream>>>(Xp, Wt2, out_b, out + (size_t)CC*S3);
}

// Round 10
// 512.596 us; speedup vs baseline: 1.3126x; 1.1698x over previous
//
#include <hip/hip_runtime.h>
#include <hip/hip_bf16.h>

#define S3 32768          // 32^3
#define PADD 34
#define PADS (34*34*34)   // 39304
#define CC 219
#define CF 64
#define CPAD 224          // padded channel count for conv inputs
#define CIN_UP 411
#define CUPAD 416         // padded channel count for upsample input
#define ALPHA 0.1f
#define EPS_IN 1e-5f

typedef __attribute__((ext_vector_type(8))) short short8;   // 8 bf16 (4 VGPRs)
typedef __attribute__((ext_vector_type(4))) float floatx4;  // 4 fp32 acc

__device__ __forceinline__ float lrelu(float v){ return v >= 0.f ? v : ALPHA * v; }
__device__ __forceinline__ unsigned short f2bf(float f){
    unsigned int u = __builtin_bit_cast(unsigned int, f);
    u = (u + 0x7FFFu + ((u >> 16) & 1u)) >> 16;   // RNE
    return (unsigned short)u;
}
// barrier that only drains LDS ops: global-load prefetch stays in flight (AITER pattern)
#define LGKM_BARRIER() __asm__ __volatile__("s_waitcnt lgkmcnt(0)\ns_barrier" ::: "memory")

// ---------------- zero-pad src to [64][34][34][34] fp32 (for corr) ----------------
__global__ __launch_bounds__(256) void pad_kernel(const float* __restrict__ src,
                                                  float* __restrict__ dst){
    int idx = blockIdx.x * 256 + threadIdx.x;
    if (idx >= CF * PADS) return;
    int c = idx / PADS, r = idx % PADS;
    int z = r / (PADD*PADD); int r2 = r % (PADD*PADD);
    int y = r2 / PADD, x = r2 % PADD;
    float v = 0.f;
    if (z >= 1 && z <= 32 && y >= 1 && y <= 32 && x >= 1 && x <= 32)
        v = src[((c*32 + (z-1))*32 + (y-1))*32 + (x-1)];
    dst[idx] = v;
}

// ---------------- correlation volume -> Xp channels [192..219) bf16 ----------------
// 512 blocks x 256 thr = 2048 waves; 64 spatial x 4 channel-groups + LDS reduction.
__global__ __launch_bounds__(256) void corr_kernel(const float* __restrict__ tgt,
                                                   const float* __restrict__ srcp,
                                                   unsigned short* __restrict__ Xp){
    __shared__ float red[3][64][27];   // groups 1..3 partials (20.7 KB)
    const int t = threadIdx.x;
    const int s = t & 63, g = t >> 6;
    const int p = blockIdx.x * 64 + s;   // 0..32767
    const int z = p >> 10, y = (p >> 5) & 31, x = p & 31;
    float acc[27];
    #pragma unroll
    for (int k = 0; k < 27; k++) acc[k] = 0.f;
    const int pbase = ((z+1)*PADD + (y+1))*PADD + (x+1);
    const int c0 = g * 16;
    for (int c = c0; c < c0 + 16; c++){
        float tv = tgt[c*S3 + p];
        const float* sp = srcp + c*PADS + pbase;
        #pragma unroll
        for (int dz = 0; dz < 3; dz++)
            #pragma unroll
            for (int dy = 0; dy < 3; dy++)
                #pragma unroll
                for (int dx = 0; dx < 3; dx++){
                    int k = (dz*3 + dy)*3 + dx;
                    acc[k] += tv * sp[(dz-1)*(PADD*PADD) + (dy-1)*PADD + (dx-1)];
                }
    }
    if (g > 0){
        #pragma unroll
        for (int k = 0; k < 27; k++) red[g-1][s][k] = acc[k];
    }
    __syncthreads();
    if (g == 0){
        #pragma unroll
        for (int k = 0; k < 27; k++)
            acc[k] += red[0][s][k] + red[1][s][k] + red[2][s][k];
        unsigned short cv[27];
        #pragma unroll
        for (int k = 0; k < 27; k++) cv[k] = f2bf(acc[k] * (1.f/64.f));
        size_t bi = ((size_t)(z+1)*1156 + (y+1)*34 + (x+1))*CPAD + 192;
        uint4 o0, o1, o2;
        o0.x = cv[0]  | ((unsigned)cv[1]<<16);  o0.y = cv[2]  | ((unsigned)cv[3]<<16);
        o0.z = cv[4]  | ((unsigned)cv[5]<<16);  o0.w = cv[6]  | ((unsigned)cv[7]<<16);
        o1.x = cv[8]  | ((unsigned)cv[9]<<16);  o1.y = cv[10] | ((unsigned)cv[11]<<16);
        o1.z = cv[12] | ((unsigned)cv[13]<<16); o1.w = cv[14] | ((unsigned)cv[15]<<16);
        o2.x = cv[16] | ((unsigned)cv[17]<<16); o2.y = cv[18] | ((unsigned)cv[19]<<16);
        o2.z = cv[20] | ((unsigned)cv[21]<<16); o2.w = cv[22] | ((unsigned)cv[23]<<16);
        *(uint4*)&Xp[bi]      = o0;
        *(uint4*)&Xp[bi + 8]  = o1;
        *(uint4*)&Xp[bi + 16] = o2;
        *(unsigned int*)&Xp[bi + 24] = cv[24] | ((unsigned)cv[25]<<16);
        Xp[bi + 26] = cv[26];
    }
}

// ---------------- instance-norm stats: one block per channel (float4 loads) ----------------
__global__ __launch_bounds__(256) void stats_kernel(const float* __restrict__ xin,
                                                    float* __restrict__ stats, int nch){
    int c = blockIdx.x;
    const float4* p = (const float4*)(xin + (size_t)c * S3);
    float s = 0.f, s2 = 0.f;
    for (int i = threadIdx.x; i < S3/4; i += 256){
        float4 v = p[i];
        s  += v.x + v.y + v.z + v.w;
        s2 += v.x*v.x + v.y*v.y + v.z*v.z + v.w*v.w;
    }
    #pragma unroll
    for (int off = 32; off > 0; off >>= 1){
        s  += __shfl_xor(s,  off);
        s2 += __shfl_xor(s2, off);
    }
    __shared__ float ls[4], ls2[4];
    int wid = threadIdx.x >> 6;
    if ((threadIdx.x & 63) == 0){ ls[wid] = s; ls2[wid] = s2; }
    __syncthreads();
    if (threadIdx.x == 0){
        float S = 0.f, S2 = 0.f;
        #pragma unroll
        for (int w = 0; w < 4; w++){ S += ls[w]; S2 += ls2[w]; }
        float m   = S * (1.f/S3);
        float var = S2 * (1.f/S3) - m*m;
        stats[c]       = m;
        stats[nch + c] = rsqrtf(var + EPS_IN);
    }
}

// ---------------- pack fp32 [C][32^3] -> channel-last bf16 Xp[34^3][224] ----------------
// optional fused fp32 normalized output (replaces the separate norm_apply pass)
__global__ __launch_bounds__(256) void pack_kernel(const float* __restrict__ src,
        const float* __restrict__ mean, const float* __restrict__ rstd,
        unsigned short* __restrict__ Xp, float* __restrict__ fp32out,
        int Csrc, int dstbase, int donorm){
    __shared__ float sT[64*33];
    const int row = blockIdx.x;          // z*32+y
    const int chunk = blockIdx.y;
    const int t = threadIdx.x;
    {
        int c = t >> 2, xq = (t & 3) * 8;
        int csrc = chunk*64 + c;
        float4 v0 = make_float4(0.f,0.f,0.f,0.f), v1 = v0;
        float m = 0.f, r = 1.f;
        if (csrc < Csrc){
            const float4* s4 = (const float4*)&src[(size_t)csrc*S3 + row*32 + xq];
            v0 = s4[0]; v1 = s4[1];
            if (donorm){ m = mean[csrc]; r = rstd[csrc]; }
        }
        if (donorm){
            v0.x = lrelu((v0.x-m)*r); v0.y = lrelu((v0.y-m)*r);
            v0.z = lrelu((v0.z-m)*r); v0.w = lrelu((v0.w-m)*r);
            v1.x = lrelu((v1.x-m)*r); v1.y = lrelu((v1.y-m)*r);
            v1.z = lrelu((v1.z-m)*r); v1.w = lrelu((v1.w-m)*r);
        }
        if (fp32out && csrc < Csrc){
            float4* o4 = (float4*)&fp32out[(size_t)csrc*S3 + row*32 + xq];
            o4[0] = v0; o4[1] = v1;
        }
        float* sp = &sT[c*33 + xq];
        sp[0]=v0.x; sp[1]=v0.y; sp[2]=v0.z; sp[3]=v0.w;
        sp[4]=v1.x; sp[5]=v1.y; sp[6]=v1.z; sp[7]=v1.w;
    }
    __syncthreads();
    {
        int x = t >> 3, coff = (t & 7) * 8;
        int dstc = dstbase + chunk*64 + coff;
        if (dstc < CPAD){
            unsigned short u[8];
            #pragma unroll
            for (int j = 0; j < 8; j++) u[j] = f2bf(sT[(coff+j)*33 + x]);
            uint4 o;
            o.x = u[0] | ((unsigned)u[1]<<16);
            o.y = u[2] | ((unsigned)u[3]<<16);
            o.z = u[4] | ((unsigned)u[5]<<16);
            o.w = u[6] | ((unsigned)u[7]<<16);
            int z = row >> 5, y = row & 31;
            size_t pos = (size_t)(z+1)*1156 + (y+1)*34 + (x+1);
            *(uint4*)&Xp[pos*CPAD + dstc] = o;
        }
    }
}

// ---------------- pack fp32 [411][16^3] -> channel-last bf16 Cp[18^3][416] ----------------
__global__ __launch_bounds__(256) void pack16_kernel(const float* __restrict__ src,
        unsigned short* __restrict__ Cp){
    __shared__ float sT[64*17];
    const int row = blockIdx.x;   // z'*16+y'
    const int chunk = blockIdx.y; // 0..6
    const int t = threadIdx.x;
    {
        int c = t >> 2, xq = (t & 3) * 4;
        int csrc = chunk*64 + c;
        float4 v = make_float4(0.f,0.f,0.f,0.f);
        if (csrc < CIN_UP)
            v = *(const float4*)&src[(size_t)csrc*4096 + row*16 + xq];
        float* sp = &sT[c*17 + xq];
        sp[0]=v.x; sp[1]=v.y; sp[2]=v.z; sp[3]=v.w;
    }
    __syncthreads();
    {
        int x = t >> 4, coff = (t & 15) * 4;
        int dstc = chunk*64 + coff;
        if (dstc < CUPAD){
            unsigned short u0 = f2bf(sT[(coff+0)*17 + x]);
            unsigned short u1 = f2bf(sT[(coff+1)*17 + x]);
            unsigned short u2 = f2bf(sT[(coff+2)*17 + x]);
            unsigned short u3 = f2bf(sT[(coff+3)*17 + x]);
            uint2 o; o.x = u0 | ((unsigned)u1<<16); o.y = u2 | ((unsigned)u3<<16);
            int z = row >> 4, y = row & 15;
            size_t pos = (size_t)(z+1)*324 + (y+1)*18 + (x+1);
            *(uint2*)&Cp[pos*CUPAD + dstc] = o;
        }
    }
}

// ---------------- pack conv weights: Wt[step=tap*7+cb][co 256][ci 32] bf16 ----------------
__global__ __launch_bounds__(256) void wpack_kernel(const float* __restrict__ w,
        unsigned short* __restrict__ Wt, int perm){
    int idx = blockIdx.x*256 + threadIdx.x;   // < 27*7*256*32
    int ciin = idx & 31;
    int co   = (idx >> 5) & 255;
    int rest = idx >> 13;        // tap*7+cb
    int cb = rest % 7, tap = rest / 7;
    int ci = cb*32 + ciin;
    float v = 0.f;
    if (co < CC && ci < CC){
        int ciref = ci;
        if (perm) ciref = ci < 128 ? ci : (ci < 192 ? ci + 27 : ci - 64);
        v = w[((size_t)co*CC + ciref)*27 + tap];
    }
    Wt[idx] = f2bf(v);
}

// ---------------- pack out-conv weights: Wt2[tap][cb][co 16][ci 32] bf16 ----------------
__global__ __launch_bounds__(256) void wpack_out_kernel(const float* __restrict__ w,
        unsigned short* __restrict__ Wt2){
    int idx = blockIdx.x*256 + threadIdx.x;   // < 27*7*16*32 = 96768
    if (idx >= 27*7*16*32) return;
    int ciin = idx & 31;
    int co   = (idx >> 5) & 15;
    int rest = idx >> 9;        // tap*7+cb
    int cb = rest % 7, tap = rest / 7;
    int ci = cb*32 + ciin;
    float v = 0.f;
    if (co < 3 && ci < CC)
        v = w[((size_t)co*CC + ci)*27 + tap];
    Wt2[idx] = f2bf(v);
}

// ---------------- pack upsample weights: Wu[parity 8][tap 8][co 64][ci 416] bf16 ----------------
__global__ __launch_bounds__(256) void wupack_kernel(const float* __restrict__ w,
        unsigned short* __restrict__ Wu){
    int idx = blockIdx.x*256 + threadIdx.x;  // < 8*8*64*416
    int ci = idx % CUPAD;
    int rest = idx / CUPAD;
    int co = rest & 63;
    int pj = rest >> 6;
    int j = pj & 7, p = pj >> 3;
    float v = 0.f;
    if (ci < CIN_UP){
        int oz = p>>2, oy = (p>>1)&1, ox = p&1;
        int jz = j>>2, jy = (j>>1)&1, jx = j&1;
        int wz = 3 - oz - 2*jz, wy = 3 - oy - 2*jy, wx = 3 - ox - 2*jx;
        v = w[(((size_t)ci*64 + co)*64) + wz*16 + wy*4 + wx];
    }
    Wu[idx] = f2bf(v);
}

// ---------------- upsample via MFMA: per-parity GEMM M=64, N=16^3, K=8*416 ----------------
// cross-barrier staging prefetch + LGKM barriers (v8, proven).
__global__ __launch_bounds__(256,2) void ups_mfma_kernel(const unsigned short* __restrict__ Cp,
        const unsigned short* __restrict__ Wu, float* __restrict__ U){
    __shared__ unsigned short sA[64*40];
    __shared__ unsigned short sB[64*40];
    const int nt = blockIdx.x;          // 512 = parity(8) x z'(16) x ygrp(4)
    const int p  = nt >> 6;
    const int zp = (nt >> 2) & 15;
    const int y0 = (nt & 3) * 4;
    const int oz = p>>2, oy = (p>>1)&1, ox = p&1;
    const int t = threadIdx.x, w = t>>6, l = t&63;
    const int mw = (w&1)*32, nw = (w>>1)*32;
    const int lm = l&15, lq = l>>4;
    const int sn = t>>2, spart = (t&3)*8;
    const int sr = sn>>4, sx = sn&15;
    floatx4 acc[2][2];
    #pragma unroll
    for (int i=0;i<2;i++)
        #pragma unroll
        for (int j=0;j<2;j++) acc[i][j] = (floatx4){0.f,0.f,0.f,0.f};

    for (int j = 0; j < 8; ++j){
        int sz = oz + (j>>2), sy = oy + ((j>>1)&1), sxx = ox + (j&1);
        size_t pbase = ((size_t)(zp+sz)*324 + (y0+sr+sy)*18 + (sx+sxx)) * CUPAD;
        size_t abase = ((size_t)(p*8 + j)*64 + sn)*CUPAD;
        uint4 av = *(const uint4*)&Wu[abase + spart];
        uint4 bv = *(const uint4*)&Cp[pbase + spart];
        for (int cb = 0; cb < 13; ++cb){
            LGKM_BARRIER();   // prior iter's ds_reads done (ds ops only; vmcnt in flight)
            *(uint4*)&sA[sn*40 + spart] = av;
            *(uint4*)&sB[sn*40 + spart] = bv;
            if (cb < 12){
                av = *(const uint4*)&Wu[abase + (cb+1)*32 + spart];
                bv = *(const uint4*)&Cp[pbase + (cb+1)*32 + spart];
            }
            LGKM_BARRIER();   // ds_writes visible; prefetch loads continue under MFMA
            short8 af[2], bfv[2];
            #pragma unroll
            for (int i=0;i<2;i++){
                af[i]  = *(const short8*)&sA[(mw + i*16 + lm)*40 + lq*8];
                bfv[i] = *(const short8*)&sB[(nw + i*16 + lm)*40 + lq*8];
            }
            #pragma unroll
            for (int i=0;i<2;i++)
                #pragma unroll
                for (int jj=0;jj<2;jj++)
                    acc[i][jj] = __builtin_amdgcn_mfma_f32_16x16x32_bf16(af[i], bfv[jj], acc[i][jj], 0,0,0);
        }
    }
    #pragma unroll
    for (int i=0;i<2;i++){
        #pragma unroll
        for (int jj=0;jj<2;jj++){
            int n = nw + jj*16 + lm;
            int yy = y0 + (n>>4), xx = n&15;
            size_t opos = ((size_t)(2*zp+oz)<<10) + ((size_t)(2*yy+oy)<<5) + (2*xx+ox);
            #pragma unroll
            for (int r=0;r<4;r++){
                int co = mw + i*16 + lq*4 + r;
                U[(size_t)co*S3 + opos] = acc[i][jj][r];
            }
        }
    }
}

// ---------------- 3x3x3 conv via MFMA: persistent B tile + deep parity pipeline ----------------
// v11 = v8 conv RESTORED (proven 126 us). Occupancy matrix is now fully mapped:
//   (512,4) cap128 -> VGPR 52 collapse (v4, 196us); (256,3) cap170 -> VGPR 80 (v9, 211us);
//   (512,2) 8-wave -> VGPR 88 (v10, 167us); (256,2) 4-wave -> VGPR 120, pipelines intact,
//   126us -- THE ONLY STABLE POINT. Do not attempt waves/SIMD > 2 in this structure.
// Structure: 3-body triplet loop (I$-safe), bf[3] B-parity dist-2, Aq[3] A-parity dist-3,
// setprio around MFMA, staging short-live-ranges, LGKM barriers (vmcnt never drained).
__global__ __launch_bounds__(256,2) void conv_mfma_kernel(const unsigned short* __restrict__ Xp,
        const unsigned short* __restrict__ Wt, const float* __restrict__ bg,
        float* __restrict__ Y){
    __shared__ unsigned short sB[612*40];   // 48,960 B
    const int nt = blockIdx.x;     // 0..255: z(32) x ygrp(8)
    const int mt = blockIdx.y;     // 0..1
    const int z  = nt >> 3;
    const int y0 = (nt & 7) * 4;
    const int t = threadIdx.x, w = t>>6, l = t&63;
    const int mw = (w & 1) * 64, nw = (w >> 1) * 64;
    const int lm = l & 15, lq = l >> 4;
    const unsigned short* ap = Wt + (size_t)(mt*128 + mw + lm)*32 + lq*8;

    // tap-invariant per-lane LDS read bases (bytes)
    int vB[4];
    #pragma unroll
    for (int j=0;j<4;j++){
        int n = nw + j*16 + lm;
        vB[j] = ((n>>5)*34 + (n&31))*80 + lq*16;
    }
    // tap-invariant staging offsets (bytes): global (relative to Xp + cb*64B) and LDS
    unsigned int goff[10]; int loff[10];
    #pragma unroll
    for (int k=0;k<10;k++){
        int idx = t + k*256;
        int p = idx >> 2, q = idx & 3;
        int zz = p / 204, rem = p % 204;
        int yy = rem / 34, x = rem - yy*34;
        goff[k] = (unsigned)((((z+zz)*1156 + (y0+yy)*34 + x)*CPAD + q*8) * 2);
        loff[k] = (p*40 + q*8) * 2;
    }
    const bool full9 = (t < 144);   // 2448 - 9*256

    floatx4 acc[4][4];
    #pragma unroll
    for (int i=0;i<4;i++)
        #pragma unroll
        for (int j=0;j<4;j++) acc[i][j] = (floatx4){0.f,0.f,0.f,0.f};

    short8 Aq[3][4];   // A parity buffers, prefetch distance 3
    short8 bf[3][4];   // B parity buffers, prefetch distance 2

    for (int cb = 0; cb < 7; ++cb){
        const unsigned short* apc = ap + (size_t)cb*8192;
        // A prologue for this cb (taps 0,1,2): issued before the barrier; latency hides
        // under staging since LGKM_BARRIER never drains vmcnt.
        #pragma unroll
        for (int i=0;i<4;i++) Aq[0][i] = *(const short8*)(apc + i*512);
        #pragma unroll
        for (int i=0;i<4;i++) Aq[1][i] = *(const short8*)(apc + (size_t)57344 + i*512);
        #pragma unroll
        for (int i=0;i<4;i++) Aq[2][i] = *(const short8*)(apc + (size_t)2*57344 + i*512);

        const char* gb = (const char*)Xp + cb*64;
        LGKM_BARRIER();   // all waves finished reading previous tile (ds ops only)
        #pragma unroll
        for (int k=0;k<9;k++){
            uint4 v = *(const uint4*)(gb + goff[k]);
            *(uint4*)((char*)sB + loff[k]) = v;
        }
        if (full9){
            uint4 v = *(const uint4*)(gb + goff[9]);
            *(uint4*)((char*)sB + loff[9]) = v;
        }
        LGKM_BARRIER();   // ds_writes visible to all waves

        // B prologue: taps 0 and 1 (toff(0)=0, toff(1)=80 bytes)
        #pragma unroll
        for (int j=0;j<4;j++) bf[0][j] = *(const short8*)((const char*)sB + vB[j]);
        #pragma unroll
        for (int j=0;j<4;j++) bf[1][j] = *(const short8*)((const char*)sB + (vB[j] + 80));

        // tap body: B-prefetch(t+2) -> [prio1] MFMA(t) [prio0] -> A-prefetch(t+3).
        #define TAP_BODY(TAP, PAR) do{                                                   \
            const int tap_ = (TAP);                                                      \
            if (tap_ < 25){                                                              \
                int t2 = tap_ + 2;                                                       \
                int toff2 = ((t2/9)*204 + ((t2/3)%3)*34 + (t2%3))*80;                    \
                _Pragma("unroll")                                                        \
                for (int j=0;j<4;j++)                                                    \
                    bf[((PAR)+2)%3][j] = *(const short8*)((const char*)sB + (vB[j] + toff2));\
            }                                                                            \
            __builtin_amdgcn_s_setprio(1);                                               \
            _Pragma("unroll")                                                            \
            for (int i=0;i<4;i++)                                                        \
                _Pragma("unroll")                                                        \
                for (int j=0;j<4;j++)                                                    \
                    acc[i][j] = __builtin_amdgcn_mfma_f32_16x16x32_bf16(                 \
                        Aq[PAR][i], bf[PAR][j], acc[i][j], 0,0,0);                       \
            __builtin_amdgcn_s_setprio(0);                                               \
            if (tap_ < 24){                                                              \
                const unsigned short* pn = apc + (size_t)(tap_+3)*57344;                 \
                _Pragma("unroll")                                                        \
                for (int i=0;i<4;i++) Aq[PAR][i] = *(const short8*)(pn + i*512);         \
            }                                                                            \
        }while(0)

        #pragma unroll 1
        for (int pr = 0; pr < 9; ++pr){
            int tap = pr*3;
            TAP_BODY(tap,   0);
            TAP_BODY(tap+1, 1);
            TAP_BODY(tap+2, 2);
        }
        #undef TAP_BODY
    }
    #pragma unroll
    for (int i=0;i<4;i++){
        #pragma unroll
        for (int j=0;j<4;j++){
            const int n = nw + j*16 + lm;
            const size_t pp = ((size_t)z<<10) + ((size_t)(y0 + (n>>5))<<5) + (n&31);
            #pragma unroll
            for (int r=0;r<4;r++){
                int gm = mt*128 + mw + i*16 + lq*4 + r;
                if (gm < CC) Y[(size_t)gm*S3 + pp] = acc[i][j][r] + bg[gm];
            }
        }
    }
}

// ---------------- final 219->3 conv: persistent spatial B tile, reg-A (27 frags) ----------------
// LGKM barriers: af weight loads stay in flight across the barrier (v8, proven).
__global__ __launch_bounds__(256,2) void convout_mfma_kernel(const unsigned short* __restrict__ Xp,
        const unsigned short* __restrict__ Wt2, const float* __restrict__ bgl,
        float* __restrict__ Y){
    __shared__ unsigned short sB[612*36];   // 44,064 B: [3z][6y][34x] x 32ci (stride 36)
    const int nt = blockIdx.x;      // z(32) x ygrp(8)
    const int z  = nt >> 3;
    const int y0 = (nt & 7) * 4;
    const int t = threadIdx.x, w = t>>6, l = t&63;
    const int nw = w * 32;
    const int lm = l & 15, lq = l >> 4;
    floatx4 acc[2];
    acc[0] = (floatx4){0.f,0.f,0.f,0.f};
    acc[1] = (floatx4){0.f,0.f,0.f,0.f};

    for (int cb = 0; cb < 7; ++cb){
        LGKM_BARRIER();   // prior iter's ds_reads done (ds ops only)
        for (int idx = t; idx < 2448; idx += 256){
            int p = idx >> 2, q = idx & 3;
            int zz = p / 204, rem = p % 204;
            int yy = rem / 34, x = rem - yy*34;
            uint4 v = *(const uint4*)&Xp[((size_t)((z+zz)*1156 + (y0+yy)*34 + x))*CPAD + cb*32 + q*8];
            *(uint4*)&sB[p*36 + q*8] = v;
        }
        short8 af[27];
        {
            const unsigned short* wp = Wt2 + ((size_t)(cb*16 + lm))*32 + lq*8;
            #pragma unroll
            for (int tap = 0; tap < 27; ++tap)
                af[tap] = *(const short8*)(wp + (size_t)tap*3584);   // 7*16*32 per tap
        }
        LGKM_BARRIER();   // ds_writes visible; af loads stay in flight
        #pragma unroll
        for (int tap = 0; tap < 27; ++tap){
            const int dz = tap/9, dy = (tap/3)%3, dx = tap%3;
            #pragma unroll
            for (int j=0;j<2;j++){
                int n = nw + j*16 + lm;
                int r = n >> 5, x = n & 31;
                short8 bf = *(const short8*)&sB[(dz*204 + (r+dy)*34 + (x+dx))*36 + lq*8];
                acc[j] = __builtin_amdgcn_mfma_f32_16x16x32_bf16(af[tap], bf, acc[j], 0,0,0);
            }
        }
    }
    if (lq == 0){
        #pragma unroll
        for (int j = 0; j < 2; j++){
            int n = nw + j*16 + lm;
            size_t pp = ((size_t)z<<10) + ((size_t)(y0 + (n>>5))<<5) + (n&31);
            #pragma unroll
            for (int r = 0; r < 3; r++)
                Y[(size_t)r*S3 + pp] = acc[j][r] + bgl[r];
        }
    }
}

extern "C" void kernel_launch(void* const* d_in, const int* in_sizes, int n_in,
                              void* d_out, int out_size, void* d_ws, size_t ws_size,
                              hipStream_t stream) {
    const float* src   = (const float*)d_in[0];
    const float* tgt   = (const float*)d_in[1];
    const float* Cmat  = (const float*)d_in[2];
    const float* up_w  = (const float*)d_in[3];
    const float* c1_w  = (const float*)d_in[5];
    const float* c1_b  = (const float*)d_in[6];
    const float* c2_w  = (const float*)d_in[7];
    const float* c2_b  = (const float*)d_in[8];
    const float* out_w = (const float*)d_in[9];
    const float* out_b = (const float*)d_in[10];

    float* out = (float*)d_out;                          // Cn [219*S3] then out [3*S3]
    char* ws = (char*)d_ws;
    unsigned short* Xp = (unsigned short*)ws;            // 34^3 x 224 bf16 = 17,608,192 B
    float*  U  = (float*)(ws + 17608192);                // 64*S3 fp32 = 8,388,608 B
    unsigned short* Wt = (unsigned short*)(ws + 17608192);       // aliases U (3,096,576 B)
    unsigned short* Cp = (unsigned short*)(ws + 25996800);       // 18^3 x 416 bf16 = 4,852,224 B
    unsigned short* Wu = (unsigned short*)(ws + 25996800 + 4852224); // 3,407,872 B
    float* srcp = (float*)(ws + 25996800);               // aliases Cp/Wu (10,061,824 B)
    unsigned short* Wt2 = (unsigned short*)(ws + 25996800); // aliases srcp after corr (193,536 B)
    float* stats = (float*)(ws + 36058624);              // 2 KB

    hipMemsetAsync(Xp, 0, 17608192, stream);             // halo + pad channels
    hipMemsetAsync(Cp, 0, 4852224, stream);

    // ---- upsample (411->64, k4 s2) as 8 parity GEMMs + instance-norm + leaky ----
    pack16_kernel<<<dim3(256,7), 256, 0, stream>>>(Cmat, Cp);
    wupack_kernel<<<6656, 256, 0, stream>>>(up_w, Wu);
    ups_mfma_kernel<<<512, 256, 0, stream>>>(Cp, Wu, U);
    stats_kernel<<<64, 256, 0, stream>>>(U, stats, 64);
    pack_kernel<<<dim3(1024,1), 256, 0, stream>>>(U, stats, stats+64, Xp, nullptr, 64, 128, 1); // Cup -> ch 128..191
    // ---- concat: tgt -> ch 0..63, src -> ch 64..127 (raw) ----
    pack_kernel<<<dim3(1024,1), 256, 0, stream>>>(tgt, nullptr, nullptr, Xp, nullptr, 64, 0, 0);
    pack_kernel<<<dim3(1024,1), 256, 0, stream>>>(src, nullptr, nullptr, Xp, nullptr, 64, 64, 0);
    // ---- correlation volume -> ch 192..218 ----
    pad_kernel<<<9826, 256, 0, stream>>>(src, srcp);
    corr_kernel<<<512, 256, 0, stream>>>(tgt, srcp, Xp);
    // ---- out-conv weight pack (srcp region is free after corr) ----
    wpack_out_kernel<<<378, 256, 0, stream>>>(out_w, Wt2);
    // ---- conv1 (219->219) MFMA ----
    wpack_kernel<<<6048, 256, 0, stream>>>(c1_w, Wt, 1);
    conv_mfma_kernel<<<dim3(256,2), 256, 0, stream>>>(Xp, Wt, c1_b, out);
    stats_kernel<<<219, 256, 0, stream>>>(out, stats, 219);
    pack_kernel<<<dim3(1024,4), 256, 0, stream>>>(out, stats, stats+219, Xp, nullptr, 219, 0, 1);
    // ---- conv2 (219->219) MFMA ----
    wpack_kernel<<<6048, 256, 0, stream>>>(c2_w, Wt, 0);
    conv_mfma_kernel<<<dim3(256,2), 256, 0, stream>>>(Xp, Wt, c2_b, out);
    // ---- norm + leaky fused: bf16 packed Cn to Xp AND fp32 Cn to d_out in one pass ----
    stats_kernel<<<219, 256, 0, stream>>>(out, stats, 219);
    pack_kernel<<<dim3(1024,4), 256, 0, stream>>>(out, stats, stats+219, Xp, out, 219, 0, 1);
    // ---- final 219->3 conv via MFMA ----
    convout_mfma_kernel<<<256, 256, 0, stream>>>(Xp, Wt2, out_b, out + (size_t)CC*S3);
}